// Round 1
// baseline (346.157 us; speedup 1.0000x reference)
//
#include <hip/hip_runtime.h>
#include <hip/hip_bf16.h>
#include <stdint.h>

typedef __bf16 bf16_t;
typedef __attribute__((ext_vector_type(8))) __bf16 bf16x8;
typedef __attribute__((ext_vector_type(4))) __bf16 bf16x4;
typedef __attribute__((ext_vector_type(4))) float f32x4;

#define S_LEN 2048
#define DMODEL 1024
#define NHEAD 16
#define DK 64
#define TENS_ELEMS 4194304   // B*S*D = 2*2048*1024

// ---------------- async global->LDS (16B per lane) ----------------
__device__ __forceinline__ void async_load16(const bf16_t* g, bf16_t* l) {
  __builtin_amdgcn_global_load_lds(
      (const __attribute__((address_space(1))) uint32_t*)(const void*)g,
      (__attribute__((address_space(3))) uint32_t*)(void*)l,
      16, 0, 0);
}

// ---------------- fp32 -> bf16 convert ----------------
__global__ __launch_bounds__(256) void cvt_kernel(const float* __restrict__ src,
                                                  bf16_t* __restrict__ dst, int n4) {
  int i = blockIdx.x * 256 + threadIdx.x;
  if (i >= n4) return;
  float4 v = ((const float4*)src)[i];
  bf16x4 o;
  o.x = (bf16_t)v.x; o.y = (bf16_t)v.y; o.z = (bf16_t)v.z; o.w = (bf16_t)v.w;
  ((bf16x4*)dst)[i] = o;
}

// ---------------- RoPE in-place on Q or K ([bh][s][64] bf16) ----------------
__global__ __launch_bounds__(256) void rope_kernel(bf16_t* __restrict__ Q,
                                                   bf16_t* __restrict__ K,
                                                   const int* __restrict__ tok) {
  int idx = blockIdx.x * 256 + threadIdx.x;   // 0 .. 32*2048*32-1
  bf16_t* T = blockIdx.y ? K : Q;
  int i  = idx & 31;            // frequency index
  int s  = (idx >> 5) & 2047;
  int bh = idx >> 16;
  float p   = (float)tok[s];
  float inv = __powf(10000.0f, -(float)i * (1.0f / 32.0f));
  float sn, cs;
  sincosf(p * inv, &sn, &cs);
  bf16_t* ptr = T + ((size_t)bh * S_LEN + s) * DK + 2 * i;
  float e = (float)ptr[0], o = (float)ptr[1];
  ptr[0] = (bf16_t)(e * cs - o * sn);
  ptr[1] = (bf16_t)(o * cs + e * sn);
}

// ---------------- V [bh][s][64] -> Vt [bh][64][2048] ----------------
__global__ __launch_bounds__(256) void transpose_v(const bf16_t* __restrict__ V,
                                                   bf16_t* __restrict__ Vt) {
  __shared__ bf16_t t[64][65];
  int bh = blockIdx.y, s0 = blockIdx.x * 64;
  int tid = threadIdx.x;
#pragma unroll
  for (int p = 0; p < 2; ++p) {
    int row = p * 32 + (tid >> 3);
    int col = (tid & 7) * 8;
    bf16x8 v = *(const bf16x8*)(V + ((size_t)bh * S_LEN + s0 + row) * DK + col);
#pragma unroll
    for (int j = 0; j < 8; ++j) t[col + j][row] = v[j];
  }
  __syncthreads();
#pragma unroll
  for (int p = 0; p < 2; ++p) {
    int d   = p * 32 + (tid >> 3);
    int col = (tid & 7) * 8;
    bf16x8 v;
#pragma unroll
    for (int j = 0; j < 8; ++j) v[j] = t[d][col + j];
    *(bf16x8*)(Vt + ((size_t)bh * DK + d) * S_LEN + s0 + col) = v;
  }
}

// ---------------- NT GEMM: C[m,n] = sum_k A[m,k]*Bw[n,k], M=4096,N=K=1024 ----
// MODE 0: write bf16 to [bh][s][dk] (QKV, blockIdx.z selects weight/output)
// MODE 1: write fp32 row-major (final projection)
template <int MODE>
__global__ __launch_bounds__(256) void gemm_nt(const bf16_t* __restrict__ A,
                                               const bf16_t* __restrict__ Bw,
                                               bf16_t* __restrict__ Cb,
                                               float* __restrict__ Cf) {
  __shared__ bf16_t As[128 * 64];
  __shared__ bf16_t Bs[128 * 64];
  const int K = 1024;
  int tid = threadIdx.x;
  int lane = tid & 63, w = tid >> 6, lo = lane & 15, hi = lane >> 4;
  int wm = w >> 1, wn = w & 1;
  int m0 = blockIdx.y * 128, n0 = blockIdx.x * 128;
  const bf16_t* Bp = Bw + (size_t)blockIdx.z * 1048576;
  f32x4 acc[4][4] = {};
  for (int k0 = 0; k0 < K; k0 += 64) {
#pragma unroll
    for (int it = 0; it < 4; ++it) {
      int idx = it * 256 + tid;
      int row = idx >> 3, kc = (idx & 7) * 8;
      async_load16(A + (size_t)(m0 + row) * K + k0 + kc, &As[idx * 8]);
      async_load16(Bp + (size_t)(n0 + row) * K + k0 + kc, &Bs[idx * 8]);
    }
    __syncthreads();
#pragma unroll
    for (int ks = 0; ks < 2; ++ks) {
      bf16x8 af[4], bfr[4];
#pragma unroll
      for (int mi = 0; mi < 4; ++mi)
        af[mi] = *(const bf16x8*)&As[(wm * 64 + mi * 16 + lo) * 64 + ks * 32 + hi * 8];
#pragma unroll
      for (int ni = 0; ni < 4; ++ni)
        bfr[ni] = *(const bf16x8*)&Bs[(wn * 64 + ni * 16 + lo) * 64 + ks * 32 + hi * 8];
#pragma unroll
      for (int mi = 0; mi < 4; ++mi)
#pragma unroll
        for (int ni = 0; ni < 4; ++ni)
          acc[mi][ni] = __builtin_amdgcn_mfma_f32_16x16x32_bf16(af[mi], bfr[ni], acc[mi][ni], 0, 0, 0);
    }
    __syncthreads();
  }
  // epilogue: C row = m0+wm*64+mi*16+hi*4+r ; col = n0+wn*64+ni*16+lo
#pragma unroll
  for (int mi = 0; mi < 4; ++mi) {
#pragma unroll
    for (int ni = 0; ni < 4; ++ni) {
      int col = n0 + wn * 64 + ni * 16 + lo;
      int rb = m0 + wm * 64 + mi * 16 + hi * 4;
      if (MODE == 0) {
        bf16_t* C = Cb + (size_t)blockIdx.z * TENS_ELEMS;
        int h = col >> 6, d = col & 63;
#pragma unroll
        for (int r = 0; r < 4; ++r) {
          int row = rb + r;
          int b = row >> 11, s = row & 2047;
          C[(((size_t)(b * NHEAD + h)) * S_LEN + s) * DK + d] = (bf16_t)acc[mi][ni][r];
        }
      } else {
#pragma unroll
        for (int r = 0; r < 4; ++r) {
          int row = rb + r;
          Cf[(size_t)row * 1024 + col] = acc[mi][ni][r];
        }
      }
    }
  }
}

// ---------------- causal flash attention ----------------
// grid (S/64, B*H); 4 waves/block; wave handles 16 q-rows.
__global__ __launch_bounds__(256) void attn_kernel(const bf16_t* __restrict__ Q,
                                                   const bf16_t* __restrict__ K,
                                                   const bf16_t* __restrict__ Vt,
                                                   bf16_t* __restrict__ O) {
  __shared__ bf16_t p_lds[4][16 * 48];
  int tid = threadIdx.x;
  int w = tid >> 6, lane = tid & 63, lo = lane & 15, hi = lane >> 4;
  int bh = blockIdx.y;
  int q0 = blockIdx.x * 64 + w * 16;
  const bf16_t* qp = Q + ((size_t)bh * S_LEN + q0 + lo) * DK + hi * 8;
  bf16x8 aq0 = *(const bf16x8*)qp;
  bf16x8 aq1 = *(const bf16x8*)(qp + 32);
  f32x4 acc[4] = {};
  float m_r[4], l_r[4];
#pragma unroll
  for (int r = 0; r < 4; ++r) { m_r[r] = -1e30f; l_r[r] = 0.0f; }

  for (int kv0 = 0; kv0 < q0 + 16; kv0 += 32) {
    const bf16_t* kp = K + ((size_t)bh * S_LEN + kv0 + lo) * DK + hi * 8;
    bf16x8 bk00 = *(const bf16x8*)kp;
    bf16x8 bk01 = *(const bf16x8*)(kp + 32);
    bf16x8 bk10 = *(const bf16x8*)(kp + 16 * DK);
    bf16x8 bk11 = *(const bf16x8*)(kp + 16 * DK + 32);
    f32x4 s0 = {0.f, 0.f, 0.f, 0.f}, s1 = {0.f, 0.f, 0.f, 0.f};
    s0 = __builtin_amdgcn_mfma_f32_16x16x32_bf16(aq0, bk00, s0, 0, 0, 0);
    s0 = __builtin_amdgcn_mfma_f32_16x16x32_bf16(aq1, bk01, s0, 0, 0, 0);
    s1 = __builtin_amdgcn_mfma_f32_16x16x32_bf16(aq0, bk10, s1, 0, 0, 0);
    s1 = __builtin_amdgcn_mfma_f32_16x16x32_bf16(aq1, bk11, s1, 0, 0, 0);

    int c0 = kv0 + lo, c1 = kv0 + 16 + lo;
    float p0[4], p1[4], al[4];
#pragma unroll
    for (int r = 0; r < 4; ++r) {
      int rowq = q0 + hi * 4 + r;
      float v0 = s0[r] * 0.125f; if (c0 > rowq) v0 = -1e9f;
      float v1 = s1[r] * 0.125f; if (c1 > rowq) v1 = -1e9f;
      float mx = fmaxf(v0, v1);
      mx = fmaxf(mx, __shfl_xor(mx, 1));
      mx = fmaxf(mx, __shfl_xor(mx, 2));
      mx = fmaxf(mx, __shfl_xor(mx, 4));
      mx = fmaxf(mx, __shfl_xor(mx, 8));
      float mn = fmaxf(m_r[r], mx);
      float a = __expf(m_r[r] - mn);
      m_r[r] = mn;
      p0[r] = __expf(v0 - mn);
      p1[r] = __expf(v1 - mn);
      float sum = p0[r] + p1[r];
      sum += __shfl_xor(sum, 1);
      sum += __shfl_xor(sum, 2);
      sum += __shfl_xor(sum, 4);
      sum += __shfl_xor(sum, 8);
      l_r[r] = l_r[r] * a + sum;
      al[r] = a;
    }
#pragma unroll
    for (int db = 0; db < 4; ++db)
#pragma unroll
      for (int r = 0; r < 4; ++r) acc[db][r] *= al[r];
    // P (16q x 32kv) -> LDS, then reload as MFMA A-frag
#pragma unroll
    for (int r = 0; r < 4; ++r) {
      p_lds[w][(hi * 4 + r) * 48 + lo]      = (bf16_t)p0[r];
      p_lds[w][(hi * 4 + r) * 48 + 16 + lo] = (bf16_t)p1[r];
    }
    bf16x8 ap = *(const bf16x8*)&p_lds[w][lo * 48 + hi * 8];
#pragma unroll
    for (int db = 0; db < 4; ++db) {
      const bf16_t* vp = Vt + ((size_t)bh * DK + db * 16 + lo) * S_LEN + kv0 + hi * 8;
      bf16x8 bv = *(const bf16x8*)vp;
      acc[db] = __builtin_amdgcn_mfma_f32_16x16x32_bf16(ap, bv, acc[db], 0, 0, 0);
    }
  }
  int b = bh >> 4, h = bh & 15;
#pragma unroll
  for (int db = 0; db < 4; ++db)
#pragma unroll
    for (int r = 0; r < 4; ++r) {
      int s = q0 + hi * 4 + r;
      O[((size_t)b * S_LEN + s) * DMODEL + h * DK + db * 16 + lo] = (bf16_t)(acc[db][r] / l_r[r]);
    }
}

extern "C" void kernel_launch(void* const* d_in, const int* in_sizes, int n_in,
                              void* d_out, int out_size, void* d_ws, size_t ws_size,
                              hipStream_t stream) {
  const float* x  = (const float*)d_in[0];
  const int* tok  = (const int*)d_in[1];
  const float* Wq = (const float*)d_in[2];
  const float* Wk = (const float*)d_in[3];
  const float* Wv = (const float*)d_in[4];
  const float* Wo = (const float*)d_in[5];
  float* out = (float*)d_out;

  bf16_t* xb  = (bf16_t*)d_ws;          // 4,194,304 elems
  bf16_t* Wb  = xb + TENS_ELEMS;        // 4 x 1,048,576
  bf16_t* Qb  = Wb + TENS_ELEMS;        // [bh][s][dk]
  bf16_t* Kb  = Qb + TENS_ELEMS;
  bf16_t* Vb  = Kb + TENS_ELEMS;
  bf16_t* Vtb = Vb + TENS_ELEMS;        // [bh][dk][s]
  bf16_t* Ab  = Vtb + TENS_ELEMS;       // attention out [b][s][1024]

  cvt_kernel<<<4096, 256, 0, stream>>>(x, xb, 1048576);
  cvt_kernel<<<1024, 256, 0, stream>>>(Wq, Wb, 262144);
  cvt_kernel<<<1024, 256, 0, stream>>>(Wk, Wb + 1048576, 262144);
  cvt_kernel<<<1024, 256, 0, stream>>>(Wv, Wb + 2097152, 262144);
  cvt_kernel<<<1024, 256, 0, stream>>>(Wo, Wb + 3145728, 262144);

  gemm_nt<0><<<dim3(8, 32, 3), 256, 0, stream>>>(xb, Wb, Qb, nullptr);
  rope_kernel<<<dim3(8192, 2), 256, 0, stream>>>(Qb, Kb, tok);
  transpose_v<<<dim3(32, 32), 256, 0, stream>>>(Vb, Vtb);
  attn_kernel<<<dim3(32, 32), 256, 0, stream>>>(Qb, Kb, Vtb, Ab);
  gemm_nt<1><<<dim3(8, 32, 1), 256, 0, stream>>>(Ab, Wb + 3145728, nullptr, out);
}

// Round 2
// 259.571 us; speedup vs baseline: 1.3336x; 1.3336x over previous
//
#include <hip/hip_runtime.h>
#include <hip/hip_bf16.h>
#include <stdint.h>

typedef __bf16 bf16_t;
typedef __attribute__((ext_vector_type(8))) __bf16 bf16x8;
typedef __attribute__((ext_vector_type(4))) __bf16 bf16x4;
typedef __attribute__((ext_vector_type(2))) __bf16 bf16x2;
typedef __attribute__((ext_vector_type(4))) float f32x4;
typedef __attribute__((ext_vector_type(16))) float f32x16;
typedef __attribute__((ext_vector_type(4))) uint32_t u32x4;

#define S_LEN 2048
#define DMODEL 1024
#define NHEAD 16
#define DK 64
#define TENS_ELEMS 4194304   // B*S*D = 2*2048*1024

// ---------------- async global->LDS (16B per lane) ----------------
__device__ __forceinline__ void async_load16(const bf16_t* g, bf16_t* l) {
  __builtin_amdgcn_global_load_lds(
      (const __attribute__((address_space(1))) uint32_t*)(const void*)g,
      (__attribute__((address_space(3))) uint32_t*)(void*)l,
      16, 0, 0);
}

__device__ __forceinline__ uint32_t pack_bf16(float a, float b) {
  bf16x2 h; h[0] = (bf16_t)a; h[1] = (bf16_t)b;
  return __builtin_bit_cast(uint32_t, h);
}

// ---------------- fp32 -> bf16 convert ----------------
__global__ __launch_bounds__(256) void cvt_kernel(const float* __restrict__ src,
                                                  bf16_t* __restrict__ dst, int n4) {
  int i = blockIdx.x * 256 + threadIdx.x;
  if (i >= n4) return;
  float4 v = ((const float4*)src)[i];
  bf16x4 o;
  o.x = (bf16_t)v.x; o.y = (bf16_t)v.y; o.z = (bf16_t)v.z; o.w = (bf16_t)v.w;
  ((bf16x4*)dst)[i] = o;
}

// ---------------- RoPE in-place on Q or K ([bh][s][64] bf16) ----------------
__global__ __launch_bounds__(256) void rope_kernel(bf16_t* __restrict__ Q,
                                                   bf16_t* __restrict__ K,
                                                   const int* __restrict__ tok) {
  int idx = blockIdx.x * 256 + threadIdx.x;   // 0 .. 32*2048*32-1
  bf16_t* T = blockIdx.y ? K : Q;
  int i  = idx & 31;            // frequency index
  int s  = (idx >> 5) & 2047;
  int bh = idx >> 16;
  float p   = (float)tok[s];
  float inv = __powf(10000.0f, -(float)i * (1.0f / 32.0f));
  float sn, cs;
  sincosf(p * inv, &sn, &cs);
  bf16_t* ptr = T + ((size_t)bh * S_LEN + s) * DK + 2 * i;
  float e = (float)ptr[0], o = (float)ptr[1];
  ptr[0] = (bf16_t)(e * cs - o * sn);
  ptr[1] = (bf16_t)(o * cs + e * sn);
}

// ---------------- V [bh][s][64] -> Vt [bh][64][2048] ----------------
__global__ __launch_bounds__(256) void transpose_v(const bf16_t* __restrict__ V,
                                                   bf16_t* __restrict__ Vt) {
  __shared__ bf16_t t[64][65];
  int bh = blockIdx.y, s0 = blockIdx.x * 64;
  int tid = threadIdx.x;
#pragma unroll
  for (int p = 0; p < 2; ++p) {
    int row = p * 32 + (tid >> 3);
    int col = (tid & 7) * 8;
    bf16x8 v = *(const bf16x8*)(V + ((size_t)bh * S_LEN + s0 + row) * DK + col);
#pragma unroll
    for (int j = 0; j < 8; ++j) t[col + j][row] = v[j];
  }
  __syncthreads();
#pragma unroll
  for (int p = 0; p < 2; ++p) {
    int d   = p * 32 + (tid >> 3);
    int col = (tid & 7) * 8;
    bf16x8 v;
#pragma unroll
    for (int j = 0; j < 8; ++j) v[j] = t[d][col + j];
    *(bf16x8*)(Vt + ((size_t)bh * DK + d) * S_LEN + s0 + col) = v;
  }
}

// ---------------- NT GEMM: C[m,n] = sum_k A[m,k]*Bw[n,k], M=4096,N=K=1024 ----
template <int MODE>
__global__ __launch_bounds__(256) void gemm_nt(const bf16_t* __restrict__ A,
                                               const bf16_t* __restrict__ Bw,
                                               bf16_t* __restrict__ Cb,
                                               float* __restrict__ Cf) {
  __shared__ bf16_t As[128 * 64];
  __shared__ bf16_t Bs[128 * 64];
  const int K = 1024;
  int tid = threadIdx.x;
  int lane = tid & 63, w = tid >> 6, lo = lane & 15, hi = lane >> 4;
  int wm = w >> 1, wn = w & 1;
  int m0 = blockIdx.y * 128, n0 = blockIdx.x * 128;
  const bf16_t* Bp = Bw + (size_t)blockIdx.z * 1048576;
  f32x4 acc[4][4] = {};
  for (int k0 = 0; k0 < K; k0 += 64) {
#pragma unroll
    for (int it = 0; it < 4; ++it) {
      int idx = it * 256 + tid;
      int row = idx >> 3, kc = (idx & 7) * 8;
      async_load16(A + (size_t)(m0 + row) * K + k0 + kc, &As[idx * 8]);
      async_load16(Bp + (size_t)(n0 + row) * K + k0 + kc, &Bs[idx * 8]);
    }
    __syncthreads();
#pragma unroll
    for (int ks = 0; ks < 2; ++ks) {
      bf16x8 af[4], bfr[4];
#pragma unroll
      for (int mi = 0; mi < 4; ++mi)
        af[mi] = *(const bf16x8*)&As[(wm * 64 + mi * 16 + lo) * 64 + ks * 32 + hi * 8];
#pragma unroll
      for (int ni = 0; ni < 4; ++ni)
        bfr[ni] = *(const bf16x8*)&Bs[(wn * 64 + ni * 16 + lo) * 64 + ks * 32 + hi * 8];
#pragma unroll
      for (int mi = 0; mi < 4; ++mi)
#pragma unroll
        for (int ni = 0; ni < 4; ++ni)
          acc[mi][ni] = __builtin_amdgcn_mfma_f32_16x16x32_bf16(af[mi], bfr[ni], acc[mi][ni], 0, 0, 0);
    }
    __syncthreads();
  }
#pragma unroll
  for (int mi = 0; mi < 4; ++mi) {
#pragma unroll
    for (int ni = 0; ni < 4; ++ni) {
      int col = n0 + wn * 64 + ni * 16 + lo;
      int rb = m0 + wm * 64 + mi * 16 + hi * 4;
      if (MODE == 0) {
        bf16_t* C = Cb + (size_t)blockIdx.z * TENS_ELEMS;
        int h = col >> 6, d = col & 63;
#pragma unroll
        for (int r = 0; r < 4; ++r) {
          int row = rb + r;
          int b = row >> 11, s = row & 2047;
          C[(((size_t)(b * NHEAD + h)) * S_LEN + s) * DK + d] = (bf16_t)acc[mi][ni][r];
        }
      } else {
#pragma unroll
        for (int r = 0; r < 4; ++r) {
          int row = rb + r;
          Cf[(size_t)row * 1024 + col] = acc[mi][ni][r];
        }
      }
    }
  }
}

// ---------------- causal flash attention, swapped-QK 32x32 form ----------------
// 1D grid of 512 blocks, 256 threads (4 waves). Each wave owns 32 q-rows.
// XCD-swizzled decode: 4 consecutive bh share one XCD (K/V stay L2-local).
// No LDS, no barriers: softmax is lane-local (lane = one q column of S^T).
__global__ __launch_bounds__(256) void attn_kernel(const bf16_t* __restrict__ Q,
                                                   const bf16_t* __restrict__ K,
                                                   const bf16_t* __restrict__ Vt,
                                                   bf16_t* __restrict__ O) {
  int tid = threadIdx.x;
  int w = tid >> 6, lane = tid & 63;
  int lq = lane & 31, hi = lane >> 5;
  int wg = blockIdx.x;
  int bh = (wg & 7) * 4 + (wg >> 7);          // XCD-pinned bh group
  int q0 = (((wg >> 3) & 15) * 4 + w) * 32;   // this wave's q-tile

  const bf16_t* Kb = K + (size_t)bh * S_LEN * DK;
  const bf16_t* Vb = Vt + (size_t)bh * DK * S_LEN;
  const bf16_t* Qp = Q + ((size_t)bh * S_LEN + q0 + lq) * DK + hi * 8;

  bf16x8 qf[4];
#pragma unroll
  for (int ks = 0; ks < 4; ++ks) qf[ks] = *(const bf16x8*)(Qp + ks * 16);

  f32x16 oa0 = {}, oa1 = {};
  float m = -1e30f, lsum = 0.f;

  for (int kv0 = 0; kv0 <= q0 + 31; kv0 += 64) {
    // ---- S^T tile: 2 sub-tiles of 32 kv, dk=64 via 4 k-slices ----
    f32x16 s0 = {}, s1 = {};
#pragma unroll
    for (int ks = 0; ks < 4; ++ks) {
      bf16x8 kf0 = *(const bf16x8*)(Kb + (size_t)(kv0 + lq) * DK + ks * 16 + hi * 8);
      s0 = __builtin_amdgcn_mfma_f32_32x32x16_bf16(kf0, qf[ks], s0, 0, 0, 0);
    }
#pragma unroll
    for (int ks = 0; ks < 4; ++ks) {
      bf16x8 kf1 = *(const bf16x8*)(Kb + (size_t)(kv0 + 32 + lq) * DK + ks * 16 + hi * 8);
      s1 = __builtin_amdgcn_mfma_f32_32x32x16_bf16(kf1, qf[ks], s1, 0, 0, 0);
    }
    // ---- scale + causal mask (lane-local: col q = q0+lq, rows = kv) ----
    float p[32];
    bool needMask = (kv0 + 63 > q0);
#pragma unroll
    for (int r = 0; r < 16; ++r) {
      float v0 = s0[r] * 0.125f, v1 = s1[r] * 0.125f;
      if (needMask) {
        int kvr = kv0 + (r & 3) + 8 * (r >> 2) + 4 * hi;
        if (kvr > q0 + lq) v0 = -1e9f;
        if (kvr + 32 > q0 + lq) v1 = -1e9f;
      }
      p[r] = v0; p[16 + r] = v1;
    }
    // ---- online softmax, lane-local + one cross-half shfl ----
    float mt = p[0];
#pragma unroll
    for (int i = 1; i < 32; ++i) mt = fmaxf(mt, p[i]);
    mt = fmaxf(mt, __shfl_xor(mt, 32));
    float mn = fmaxf(m, mt);
    float a = __expf(m - mn);
    m = mn;
    float sum = 0.f;
#pragma unroll
    for (int i = 0; i < 32; ++i) { p[i] = __expf(p[i] - mn); sum += p[i]; }
    sum += __shfl_xor(sum, 32);
    lsum = lsum * a + sum;
#pragma unroll
    for (int r = 0; r < 16; ++r) { oa0[r] *= a; oa1[r] *= a; }
    // ---- pack P to bf16 pairs + cross-half exchange (no LDS) ----
    uint32_t pk[16], xk[16];
#pragma unroll
    for (int c = 0; c < 16; ++c) pk[c] = pack_bf16(p[2 * c], p[2 * c + 1]);
#pragma unroll
    for (int c = 0; c < 16; ++c) xk[c] = (uint32_t)__shfl_xor((int)pk[c], 32);
    // ---- PV: O^T[d][q] += V^T[d][kv] * P^T[kv][q] ----
#pragma unroll
    for (int t = 0; t < 2; ++t)
#pragma unroll
      for (int j = 0; j < 2; ++j) {
        int c0 = 8 * t + 4 * j;
        uint32_t b0 = hi ? xk[c0 + 2] : pk[c0];
        uint32_t b1 = hi ? xk[c0 + 3] : pk[c0 + 1];
        uint32_t b2 = hi ? pk[c0 + 2] : xk[c0];
        uint32_t b3 = hi ? pk[c0 + 3] : xk[c0 + 1];
        u32x4 bb = {b0, b1, b2, b3};
        bf16x8 pb = __builtin_bit_cast(bf16x8, bb);
        int kvb = kv0 + 32 * t + 16 * j + hi * 8;
        bf16x8 vf0 = *(const bf16x8*)(Vb + (size_t)lq * S_LEN + kvb);
        oa0 = __builtin_amdgcn_mfma_f32_32x32x16_bf16(vf0, pb, oa0, 0, 0, 0);
        bf16x8 vf1 = *(const bf16x8*)(Vb + (size_t)(32 + lq) * S_LEN + kvb);
        oa1 = __builtin_amdgcn_mfma_f32_32x32x16_bf16(vf1, pb, oa1, 0, 0, 0);
      }
  }
  // ---- epilogue: O^T regs -> [b][s][h*64+d], 8B packed stores ----
  float inv = 1.0f / lsum;
  int b = bh >> 4, h = bh & 15;
  bf16_t* Op = O + ((size_t)(b * S_LEN + q0 + lq)) * DMODEL + h * 64;
#pragma unroll
  for (int g = 0; g < 4; ++g) {
    bf16x4 ov0, ov1;
#pragma unroll
    for (int i = 0; i < 4; ++i) {
      ov0[i] = (bf16_t)(oa0[4 * g + i] * inv);
      ov1[i] = (bf16_t)(oa1[4 * g + i] * inv);
    }
    *(bf16x4*)(Op + 8 * g + 4 * hi) = ov0;
    *(bf16x4*)(Op + 32 + 8 * g + 4 * hi) = ov1;
  }
}

extern "C" void kernel_launch(void* const* d_in, const int* in_sizes, int n_in,
                              void* d_out, int out_size, void* d_ws, size_t ws_size,
                              hipStream_t stream) {
  const float* x  = (const float*)d_in[0];
  const int* tok  = (const int*)d_in[1];
  const float* Wq = (const float*)d_in[2];
  const float* Wk = (const float*)d_in[3];
  const float* Wv = (const float*)d_in[4];
  const float* Wo = (const float*)d_in[5];
  float* out = (float*)d_out;

  bf16_t* xb  = (bf16_t*)d_ws;          // 4,194,304 elems
  bf16_t* Wb  = xb + TENS_ELEMS;        // 4 x 1,048,576
  bf16_t* Qb  = Wb + TENS_ELEMS;        // [bh][s][dk]
  bf16_t* Kb  = Qb + TENS_ELEMS;
  bf16_t* Vb  = Kb + TENS_ELEMS;
  bf16_t* Vtb = Vb + TENS_ELEMS;        // [bh][dk][s]
  bf16_t* Ab  = Vtb + TENS_ELEMS;       // attention out [b][s][1024]

  cvt_kernel<<<4096, 256, 0, stream>>>(x, xb, 1048576);
  cvt_kernel<<<1024, 256, 0, stream>>>(Wq, Wb, 262144);
  cvt_kernel<<<1024, 256, 0, stream>>>(Wk, Wb + 1048576, 262144);
  cvt_kernel<<<1024, 256, 0, stream>>>(Wv, Wb + 2097152, 262144);
  cvt_kernel<<<1024, 256, 0, stream>>>(Wo, Wb + 3145728, 262144);

  gemm_nt<0><<<dim3(8, 32, 3), 256, 0, stream>>>(xb, Wb, Qb, nullptr);
  rope_kernel<<<dim3(8192, 2), 256, 0, stream>>>(Qb, Kb, tok);
  transpose_v<<<dim3(32, 32), 256, 0, stream>>>(Vb, Vtb);
  attn_kernel<<<512, 256, 0, stream>>>(Qb, Kb, Vtb, Ab);
  gemm_nt<1><<<dim3(8, 32, 1), 256, 0, stream>>>(Ab, Wb + 3145728, nullptr, out);
}

// Round 3
// 222.438 us; speedup vs baseline: 1.5562x; 1.1669x over previous
//
#include <hip/hip_runtime.h>
#include <hip/hip_bf16.h>
#include <stdint.h>

typedef __bf16 bf16_t;
typedef __attribute__((ext_vector_type(8))) __bf16 bf16x8;
typedef __attribute__((ext_vector_type(4))) __bf16 bf16x4;
typedef __attribute__((ext_vector_type(2))) __bf16 bf16x2;
typedef __attribute__((ext_vector_type(4))) float f32x4;
typedef __attribute__((ext_vector_type(16))) float f32x16;
typedef __attribute__((ext_vector_type(4))) uint32_t u32x4;

#define S_LEN 2048
#define DMODEL 1024
#define NHEAD 16
#define DK 64
#define TENS_ELEMS 4194304   // B*S*D = 2*2048*1024

// ---------------- async global->LDS (16B per lane) ----------------
__device__ __forceinline__ void async_load16(const bf16_t* g, bf16_t* l) {
  __builtin_amdgcn_global_load_lds(
      (const __attribute__((address_space(1))) uint32_t*)(const void*)g,
      (__attribute__((address_space(3))) uint32_t*)(void*)l,
      16, 0, 0);
}

__device__ __forceinline__ uint32_t pack_bf16(float a, float b) {
  bf16x2 h; h[0] = (bf16_t)a; h[1] = (bf16_t)b;
  return __builtin_bit_cast(uint32_t, h);
}

// ---------------- fp32 -> bf16 convert ----------------
__global__ __launch_bounds__(256) void cvt_kernel(const float* __restrict__ src,
                                                  bf16_t* __restrict__ dst, int n4) {
  int i = blockIdx.x * 256 + threadIdx.x;
  if (i >= n4) return;
  float4 v = ((const float4*)src)[i];
  bf16x4 o;
  o.x = (bf16_t)v.x; o.y = (bf16_t)v.y; o.z = (bf16_t)v.z; o.w = (bf16_t)v.w;
  ((bf16x4*)dst)[i] = o;
}

// ---------------- RoPE in-place on Q or K ([bh][s][64] bf16) ----------------
__global__ __launch_bounds__(256) void rope_kernel(bf16_t* __restrict__ Q,
                                                   bf16_t* __restrict__ K,
                                                   const int* __restrict__ tok) {
  int idx = blockIdx.x * 256 + threadIdx.x;   // 0 .. 32*2048*32-1
  bf16_t* T = blockIdx.y ? K : Q;
  int i  = idx & 31;            // frequency index
  int s  = (idx >> 5) & 2047;
  int bh = idx >> 16;
  float p   = (float)tok[s];
  float inv = __powf(10000.0f, -(float)i * (1.0f / 32.0f));
  float sn, cs;
  sincosf(p * inv, &sn, &cs);
  bf16_t* ptr = T + ((size_t)bh * S_LEN + s) * DK + 2 * i;
  float e = (float)ptr[0], o = (float)ptr[1];
  ptr[0] = (bf16_t)(e * cs - o * sn);
  ptr[1] = (bf16_t)(o * cs + e * sn);
}

// ---------------- NT GEMM: C[m,n] = sum_k A[m,k]*Bw[n,k], M=4096,N=K=1024 ----
// MODE 0: z=0/1 -> bf16 [bh][s][dk]; z=2 -> bf16 transposed [bh][dk][s] (Vt)
// MODE 1: fp32 row-major (final projection)
template <int MODE>
__global__ __launch_bounds__(256) void gemm_nt(const bf16_t* __restrict__ A,
                                               const bf16_t* __restrict__ Bw,
                                               bf16_t* __restrict__ Cb,
                                               float* __restrict__ Cf) {
  __shared__ bf16_t As[128 * 64];
  __shared__ bf16_t Bs[128 * 64];
  const int K = 1024;
  int tid = threadIdx.x;
  int lane = tid & 63, w = tid >> 6, lo = lane & 15, hi = lane >> 4;
  int wm = w >> 1, wn = w & 1;
  int m0 = blockIdx.y * 128, n0 = blockIdx.x * 128;
  const bf16_t* Bp = Bw + (size_t)blockIdx.z * 1048576;
  f32x4 acc[4][4] = {};
  for (int k0 = 0; k0 < K; k0 += 64) {
#pragma unroll
    for (int it = 0; it < 4; ++it) {
      int idx = it * 256 + tid;
      int row = idx >> 3, kc = (idx & 7) * 8;
      async_load16(A + (size_t)(m0 + row) * K + k0 + kc, &As[idx * 8]);
      async_load16(Bp + (size_t)(n0 + row) * K + k0 + kc, &Bs[idx * 8]);
    }
    __syncthreads();
#pragma unroll
    for (int ks = 0; ks < 2; ++ks) {
      bf16x8 af[4], bfr[4];
#pragma unroll
      for (int mi = 0; mi < 4; ++mi)
        af[mi] = *(const bf16x8*)&As[(wm * 64 + mi * 16 + lo) * 64 + ks * 32 + hi * 8];
#pragma unroll
      for (int ni = 0; ni < 4; ++ni)
        bfr[ni] = *(const bf16x8*)&Bs[(wn * 64 + ni * 16 + lo) * 64 + ks * 32 + hi * 8];
#pragma unroll
      for (int mi = 0; mi < 4; ++mi)
#pragma unroll
        for (int ni = 0; ni < 4; ++ni)
          acc[mi][ni] = __builtin_amdgcn_mfma_f32_16x16x32_bf16(af[mi], bfr[ni], acc[mi][ni], 0, 0, 0);
    }
    __syncthreads();
  }
#pragma unroll
  for (int mi = 0; mi < 4; ++mi) {
#pragma unroll
    for (int ni = 0; ni < 4; ++ni) {
      int col = n0 + wn * 64 + ni * 16 + lo;
      int rb = m0 + wm * 64 + mi * 16 + hi * 4;
      if (MODE == 0) {
        int h = col >> 6, d = col & 63;
        if (blockIdx.z == 2) {
          // V: write transposed [bh][d][s] with one 8B store (s-contiguous)
          bf16_t* Vt = Cb + 3 * (size_t)TENS_ELEMS;
          int b = rb >> 11, s = rb & 2047;
          bf16x4 ov;
#pragma unroll
          for (int r = 0; r < 4; ++r) ov[r] = (bf16_t)acc[mi][ni][r];
          *(bf16x4*)(Vt + (((size_t)(b * NHEAD + h)) * DK + d) * S_LEN + s) = ov;
        } else {
          bf16_t* C = Cb + (size_t)blockIdx.z * TENS_ELEMS;
#pragma unroll
          for (int r = 0; r < 4; ++r) {
            int row = rb + r;
            int b = row >> 11, s = row & 2047;
            C[(((size_t)(b * NHEAD + h)) * S_LEN + s) * DK + d] = (bf16_t)acc[mi][ni][r];
          }
        }
      } else {
#pragma unroll
        for (int r = 0; r < 4; ++r) {
          int row = rb + r;
          Cf[(size_t)row * 1024 + col] = acc[mi][ni][r];
        }
      }
    }
  }
}

// ---------------- causal flash attention, swapped-QK 32x32 form ----------------
// 1D grid of 512 blocks, 256 threads (4 waves). Each wave owns 32 q-rows.
// No LDS, no barriers. launch_bounds(...,1) -> full VGPR budget, no scratch spill.
// K-frags double-buffered in regs (prefetch next tile under softmax VALU phase);
// V-frags prefetched before softmax. Tree max/sum; defer-max rescale skip (exact).
__global__ __launch_bounds__(256, 1) void attn_kernel(const bf16_t* __restrict__ Q,
                                                      const bf16_t* __restrict__ K,
                                                      const bf16_t* __restrict__ Vt,
                                                      bf16_t* __restrict__ O) {
  int tid = threadIdx.x;
  int w = tid >> 6, lane = tid & 63;
  int lq = lane & 31, hi = lane >> 5;
  int wg = blockIdx.x;
  int bh = (wg & 7) * 4 + (wg >> 7);          // XCD-pinned bh group
  int q0 = (((wg >> 3) & 15) * 4 + w) * 32;   // this wave's q-tile

  const bf16_t* Kb = K + (size_t)bh * S_LEN * DK;
  const bf16_t* Vb = Vt + (size_t)bh * DK * S_LEN;
  const bf16_t* Qp = Q + ((size_t)bh * S_LEN + q0 + lq) * DK + hi * 8;

  bf16x8 qf[4];
#pragma unroll
  for (int ks = 0; ks < 4; ++ks) qf[ks] = *(const bf16x8*)(Qp + ks * 16);

  f32x16 oa0 = {}, oa1 = {};
  float m = -1e30f, lsum = 0.f;

  const bf16_t* kp = Kb + (size_t)lq * DK + hi * 8;  // lane-base into K
  // prefetch tile 0 K-fragments: idx = (sub<<2)|ks, sub: rows +0/+32
  bf16x8 kc[8];
#pragma unroll
  for (int i = 0; i < 8; ++i)
    kc[i] = *(const bf16x8*)(kp + (size_t)(i >> 2) * 32 * DK + (i & 3) * 16);

  int nTiles = (q0 + 32 + 63) >> 6;
  for (int t = 0; t < nTiles; ++t) {
    int kv0 = t * 64;
    // ---- S^T = K * Q ----
    f32x16 s0 = {}, s1 = {};
#pragma unroll
    for (int ks = 0; ks < 4; ++ks)
      s0 = __builtin_amdgcn_mfma_f32_32x32x16_bf16(kc[ks], qf[ks], s0, 0, 0, 0);
#pragma unroll
    for (int ks = 0; ks < 4; ++ks)
      s1 = __builtin_amdgcn_mfma_f32_32x32x16_bf16(kc[4 + ks], qf[ks], s1, 0, 0, 0);
    // ---- prefetch next K tile (in flight during softmax) ----
    bf16x8 kn[8];
    bool more = (t + 1 < nTiles);
    if (more) {
      const bf16_t* kpn = kp + (size_t)(kv0 + 64) * DK;
#pragma unroll
      for (int i = 0; i < 8; ++i)
        kn[i] = *(const bf16x8*)(kpn + (size_t)(i >> 2) * 32 * DK + (i & 3) * 16);
    }
    // ---- prefetch V fragments for this tile ----
    bf16x8 vf[8];   // [sub(0/1: d 0-31 / 32-63)][u: kv offset 16u + 8hi]
#pragma unroll
    for (int sub = 0; sub < 2; ++sub)
#pragma unroll
      for (int u = 0; u < 4; ++u)
        vf[sub * 4 + u] = *(const bf16x8*)(Vb + (size_t)(32 * sub + lq) * S_LEN + kv0 + 16 * u + 8 * hi);
    // ---- scale + causal mask (lane-local) ----
    float p[32];
    bool needMask = (kv0 + 63 > q0);
#pragma unroll
    for (int r = 0; r < 16; ++r) {
      float v0 = s0[r] * 0.125f, v1 = s1[r] * 0.125f;
      if (needMask) {
        int kvr = kv0 + (r & 3) + 8 * (r >> 2) + 4 * hi;
        if (kvr > q0 + lq) v0 = -1e9f;
        if (kvr + 32 > q0 + lq) v1 = -1e9f;
      }
      p[r] = v0; p[16 + r] = v1;
    }
    // ---- tree max (depth 5) + cross-half ----
    float tm[16];
#pragma unroll
    for (int i = 0; i < 16; ++i) tm[i] = fmaxf(p[i], p[16 + i]);
#pragma unroll
    for (int i = 0; i < 8; ++i) tm[i] = fmaxf(tm[i], tm[8 + i]);
#pragma unroll
    for (int i = 0; i < 4; ++i) tm[i] = fmaxf(tm[i], tm[4 + i]);
    float mt = fmaxf(fmaxf(tm[0], tm[1]), fmaxf(tm[2], tm[3]));
    mt = fmaxf(mt, __shfl_xor(mt, 32));
    // ---- defer-max: only rescale when running max grows (exact, THR=0) ----
    if (__any(mt > m)) {
      float mn = fmaxf(m, mt);
      float a = __expf(m - mn);
      m = mn;
      lsum *= a;
#pragma unroll
      for (int r = 0; r < 16; ++r) { oa0[r] *= a; oa1[r] *= a; }
    }
    // ---- exp + tree sum ----
    float ts[16];
#pragma unroll
    for (int i = 0; i < 32; ++i) p[i] = __expf(p[i] - m);
#pragma unroll
    for (int i = 0; i < 16; ++i) ts[i] = p[i] + p[16 + i];
#pragma unroll
    for (int i = 0; i < 8; ++i) ts[i] += ts[8 + i];
#pragma unroll
    for (int i = 0; i < 4; ++i) ts[i] += ts[4 + i];
    float sum = (ts[0] + ts[1]) + (ts[2] + ts[3]);
    sum += __shfl_xor(sum, 32);
    lsum += sum;
    // ---- pack P to bf16 pairs + cross-half exchange (no LDS) ----
    uint32_t pk[16], xk[16];
#pragma unroll
    for (int c = 0; c < 16; ++c) pk[c] = pack_bf16(p[2 * c], p[2 * c + 1]);
#pragma unroll
    for (int c = 0; c < 16; ++c) xk[c] = (uint32_t)__shfl_xor((int)pk[c], 32);
    // ---- PV: O^T[d][q] += V^T[d][kv] * P^T[kv][q] ----
#pragma unroll
    for (int tt = 0; tt < 2; ++tt)
#pragma unroll
      for (int j = 0; j < 2; ++j) {
        int c0 = 8 * tt + 4 * j;
        uint32_t b0 = hi ? xk[c0 + 2] : pk[c0];
        uint32_t b1 = hi ? xk[c0 + 3] : pk[c0 + 1];
        uint32_t b2 = hi ? pk[c0 + 2] : xk[c0];
        uint32_t b3 = hi ? pk[c0 + 3] : xk[c0 + 1];
        u32x4 bb = {b0, b1, b2, b3};
        bf16x8 pb = __builtin_bit_cast(bf16x8, bb);
        int u = 2 * tt + j;
        oa0 = __builtin_amdgcn_mfma_f32_32x32x16_bf16(vf[u], pb, oa0, 0, 0, 0);
        oa1 = __builtin_amdgcn_mfma_f32_32x32x16_bf16(vf[4 + u], pb, oa1, 0, 0, 0);
      }
    // ---- rotate K double-buffer ----
    if (more) {
#pragma unroll
      for (int i = 0; i < 8; ++i) kc[i] = kn[i];
    }
  }
  // ---- epilogue: O^T regs -> [b][s][h*64+d], 8B packed stores ----
  float inv = 1.0f / lsum;
  int b = bh >> 4, h = bh & 15;
  bf16_t* Op = O + ((size_t)(b * S_LEN + q0 + lq)) * DMODEL + h * 64;
#pragma unroll
  for (int g = 0; g < 4; ++g) {
    bf16x4 ov0, ov1;
#pragma unroll
    for (int i = 0; i < 4; ++i) {
      ov0[i] = (bf16_t)(oa0[4 * g + i] * inv);
      ov1[i] = (bf16_t)(oa1[4 * g + i] * inv);
    }
    *(bf16x4*)(Op + 8 * g + 4 * hi) = ov0;
    *(bf16x4*)(Op + 32 + 8 * g + 4 * hi) = ov1;
  }
}

extern "C" void kernel_launch(void* const* d_in, const int* in_sizes, int n_in,
                              void* d_out, int out_size, void* d_ws, size_t ws_size,
                              hipStream_t stream) {
  const float* x  = (const float*)d_in[0];
  const int* tok  = (const int*)d_in[1];
  const float* Wq = (const float*)d_in[2];
  const float* Wk = (const float*)d_in[3];
  const float* Wv = (const float*)d_in[4];
  const float* Wo = (const float*)d_in[5];
  float* out = (float*)d_out;

  bf16_t* xb  = (bf16_t*)d_ws;          // 4,194,304 elems
  bf16_t* Wb  = xb + TENS_ELEMS;        // 4 x 1,048,576
  bf16_t* Qb  = Wb + TENS_ELEMS;        // [bh][s][dk]
  bf16_t* Kb  = Qb + TENS_ELEMS;
  bf16_t* Vb  = Kb + TENS_ELEMS;        // (unused slot)
  bf16_t* Vtb = Vb + TENS_ELEMS;        // [bh][dk][s], written by gemm z==2
  bf16_t* Ab  = Vtb + TENS_ELEMS;       // attention out [b][s][1024]

  cvt_kernel<<<4096, 256, 0, stream>>>(x, xb, 1048576);
  cvt_kernel<<<1024, 256, 0, stream>>>(Wq, Wb, 262144);
  cvt_kernel<<<1024, 256, 0, stream>>>(Wk, Wb + 1048576, 262144);
  cvt_kernel<<<1024, 256, 0, stream>>>(Wv, Wb + 2097152, 262144);
  cvt_kernel<<<1024, 256, 0, stream>>>(Wo, Wb + 3145728, 262144);

  gemm_nt<0><<<dim3(8, 32, 3), 256, 0, stream>>>(xb, Wb, Qb, nullptr);
  rope_kernel<<<dim3(8192, 2), 256, 0, stream>>>(Qb, Kb, tok);
  attn_kernel<<<512, 256, 0, stream>>>(Qb, Kb, Vtb, Ab);
  gemm_nt<1><<<dim3(8, 32, 1), 256, 0, stream>>>(Ab, Wb + 3145728, nullptr, out);
}